// Round 9
// baseline (154.604 us; speedup 1.0000x reference)
//
#include <hip/hip_runtime.h>
#include <cstdint>
#include <cstddef>

// Problem constants
#define B_    16
#define S_    1024
#define D_    768
#define NS_   256
#define V_    128
#define C_    6
#define R_    512
#define REL_  97
#define HID_  384
#define DIS_  20
#define K1_   2344   // true feat width
#define KP_   2432   // permuted+padded K (38*64) -> 19 iters per split-K slice
#define NIT_  38
#define N2P_  128    // gemm2 padded N

#define BM1   128
#define BN1   64
#define SLICE_ ((size_t)8192 * HID_)   // one split-K partial (bf16 elems)

typedef unsigned short ushort_t;
typedef unsigned int   u32;
typedef short bf16x4 __attribute__((ext_vector_type(4)));
typedef short bf16x8 __attribute__((ext_vector_type(8)));
typedef float f32x4  __attribute__((ext_vector_type(4)));
typedef float f32x16 __attribute__((ext_vector_type(16)));

__device__ __forceinline__ float bf2f(short s) {
    return __uint_as_float(((unsigned int)(unsigned short)s) << 16);
}
__device__ __forceinline__ short f2bf(float x) {   // RNE
    union { float f; unsigned int u; } c; c.f = x;
    unsigned int r = (c.u + 0x7fffu + ((c.u >> 16) & 1u)) >> 16;
    return (short)(unsigned short)r;
}

// async global->LDS, 16 B per lane; LDS dest = wave-uniform base + lane*16
typedef const __attribute__((address_space(1))) u32* gas_t;
typedef __attribute__((address_space(3))) u32*       las_t;
__device__ __forceinline__ void dma16(const void* g, void* l) {
    __builtin_amdgcn_global_load_lds((gas_t)g, (las_t)l, 16, 0, 0);
}

__device__ __forceinline__ int w1_orig(int k) {
    if      (k < 768)  return k;
    else if (k < 1536) return k + 20;
    else if (k < 2304) return k + 40;
    else if (k < 2324) return 768 + (k - 2304);
    else if (k < K1_)  return 1556 + (k - 2324);
    return -1;
}

// ---------------------------------------------------------------------------
// Kernel A (prep), 192 threads, ILP-structured (all loads independent):
//  blocks [0,4096): span max-pool — 8 rows loaded UNCONDITIONALLY as f32x4
//    (always in-bounds since start <= S-MAXW), predicated max.
//  blocks [4096,4704): W1 -> W1Tile [it][nt(6)][kg][nn(64)][8], one bf16x8
//    granule per thread (8 coalesced loads + one 16 B store).
//  blocks [4704,4736): W2 (384x97) -> W2T (128x384, n-padded), one granule
//    per thread.
// ---------------------------------------------------------------------------
__global__ __launch_bounds__(192) void prep_kernel(
    const float* __restrict__ sr, const int* __restrict__ spans,
    const float* __restrict__ W1, const float* __restrict__ W2,
    ushort_t* __restrict__ span_emb, ushort_t* __restrict__ W1Tile,
    ushort_t* __restrict__ W2T)
{
    int blk = blockIdx.x;
    int tid = threadIdx.x;
    if (blk < 4096) {
        int bn    = blk;
        int b     = bn >> 8;                 // NS = 256
        int start = spans[2 * bn];
        int end   = spans[2 * bn + 1];
        int w     = end - start;             // 0..7, block-uniform
        const float* base = sr + ((size_t)b * S_ + start) * D_ + tid * 4;
        f32x4 x[8];
#pragma unroll
        for (int j = 0; j < 8; ++j)          // independent: one waitcnt round
            x[j] = *(const f32x4*)(base + (size_t)j * D_);
        f32x4 m = x[0];
#pragma unroll
        for (int j = 1; j < 8; ++j)
            if (j <= w) {                    // block-uniform predication
#pragma unroll
                for (int c = 0; c < 4; ++c) m[c] = fmaxf(m[c], x[j][c]);
            }
        bf16x4 o;
#pragma unroll
        for (int c = 0; c < 4; ++c) o[c] = f2bf(m[c]);
        *(bf16x4*)(span_emb + (size_t)bn * D_ + tid * 4) = o;
    } else if (blk < 4096 + 608) {
        int flat = (blk - 4096) * 192 + tid; // 0..116735 = 38*6*8*64
        int nn   = flat & 63;
        int kg   = (flat >> 6) & 7;
        int itnt = flat >> 9;                // it*6 + nt, 0..227
        int it   = itnt / 6;
        bf16x8 p;
#pragma unroll
        for (int j = 0; j < 8; ++j) {
            int k = it * 64 + kg * 8 + j;
            int orig = w1_orig(k);
            int n    = (itnt - it * 6) * 64 + nn;
            float v = (orig >= 0) ? W1[(size_t)orig * HID_ + n] : 0.f;
            p[j] = f2bf(v);
        }
        *(bf16x8*)(W1Tile + ((size_t)itnt * 8 + kg) * 512 + nn * 8) = p;
    } else {
        int g  = (blk - 4704) * 192 + tid;   // 0..6143 = 128*384/8
        int n  = g / 48;                     // 0..127
        int k0 = (g - n * 48) * 8;
        bf16x8 p;
#pragma unroll
        for (int j = 0; j < 8; ++j) {
            float v = (n < REL_) ? W2[(size_t)(k0 + j) * REL_ + n] : 0.f;
            p[j] = f2bf(v);
        }
        *(bf16x8*)(W2T + (size_t)n * HID_ + k0) = p;
    }
}

// ---------------------------------------------------------------------------
// Kernel 2: vertex mean (bf16 in/out, f32 accumulate, bf16x4 vectorized).
// ---------------------------------------------------------------------------
__global__ __launch_bounds__(192) void vertex_kernel(
    const ushort_t* __restrict__ span_emb, const int* __restrict__ vidx,
    const int* __restrict__ vmask, ushort_t* __restrict__ vembB)
{
    int bv = blockIdx.x;
    int b  = bv >> 7;                // V = 128
    const int* vi = vidx  + bv * C_;
    const int* vm = vmask + bv * C_;
    int   idxs[C_];
    float ms[C_];
    float cnt = 0.f;
#pragma unroll
    for (int c = 0; c < C_; ++c) {
        idxs[c] = vi[c];
        ms[c]   = (float)vm[c];
        cnt    += ms[c];
    }
    float inv = 1.f / fmaxf(cnt, 1.f);
    int col = threadIdx.x * 4;
    float s[4] = {0.f, 0.f, 0.f, 0.f};
#pragma unroll
    for (int c = 0; c < C_; ++c) {
        if (ms[c] != 0.f) {          // block-uniform branch
            bf16x4 x = *(const bf16x4*)(span_emb +
                        ((size_t)(b * NS_ + idxs[c])) * D_ + col);
#pragma unroll
            for (int q = 0; q < 4; ++q) s[q] += bf2f(x[q]);
        }
    }
    bf16x4 o;
#pragma unroll
    for (int q = 0; q < 4; ++q) o[q] = f2bf(s[q] * inv);
    *(bf16x4*)(vembB + (size_t)bv * D_ + col) = o;
}

// ---------------------------------------------------------------------------
// Kernel 3: fused-gather MFMA GEMM1, split-K=2 (parity-interleaved iters),
// bf16 partials, plain stores.
// Block 128m x 64n; 4 waves (2x2) each 64m x 32n via 2x1 of 32x32x16 MFMA.
// Grid 64 x 6 x 2 = 768 blocks; LDS 48 KB -> exactly 3 blocks/CU, no tail.
// A LDS: swizzled row-major Abuf[row][64], granule g of row r at slot (g+r)&7:
//   DMA lane-linear (8 rows x 8 slots per inst, adjacent lanes cover one
//   row's contiguous 128 B); fragment ds_read_b128 conflict-free via rotation.
// B LDS: granule-plane Bbuf[kg][64][8] (DMA 1 KB contiguous per inst from
//   retiled W1Tile).
// Double-buffered, one barrier/iter, DMA issued post-barrier.
// ---------------------------------------------------------------------------
__global__ __launch_bounds__(256, 3) void gemm1_kernel(
    const ushort_t* __restrict__ vembB, const int* __restrict__ ht,
    const int* __restrict__ dht, const int* __restrict__ dth,
    const float* __restrict__ dis, const ushort_t* __restrict__ W1Tile,
    ushort_t* __restrict__ hiddenS)
{
    __shared__ ushort_t Abuf[2][BM1][64];       // 32 KB (swizzled slots)
    __shared__ ushort_t Bbuf[2][8][BN1][8];     // 16 KB

    int tid  = threadIdx.x;
    int wv   = tid >> 6;
    int lane = tid & 63;
    int m0   = blockIdx.x * BM1;
    int n0   = blockIdx.y * BN1;
    int nt   = blockIdx.y;
    int ksl  = blockIdx.z;                    // 0/1: parity of iters

    int rr  = lane >> 3;                      // row-in-group 0..7
    int sl  = lane & 7;                       // LDS slot 0..7
    int gsw = (sl - rr) & 7;                  // granule this lane fetches

    // per-lane row offsets for its 4 staging rows (element offsets in vembB)
    int hoff[4], toff[4];
#pragma unroll
    for (int gi = 0; gi < 4; ++gi) {
        int row = wv * 32 + gi * 8 + rr;
        int g   = m0 + row;
        int b   = g >> 9;                     // R = 512
        hoff[gi] = (b * V_ + ht[2 * g])     * D_;
        toff[gi] = (b * V_ + ht[2 * g + 1]) * D_;
    }

    auto stage = [&](int bf, int it_g) {
        int k0   = it_g * 64;
        int r    = k0 / 768;                  // block-uniform region id
        int koff = k0 - r * 768;
        int kk   = koff + gsw * 8;            // lane's element offset in region
        if (r == 0) {
#pragma unroll
            for (int gi = 0; gi < 4; ++gi)
                dma16(vembB + hoff[gi] + kk, &Abuf[bf][wv * 32 + gi * 8][0]);
        } else if (r == 1) {
#pragma unroll
            for (int gi = 0; gi < 4; ++gi)
                dma16(vembB + toff[gi] + kk, &Abuf[bf][wv * 32 + gi * 8][0]);
        } else if (r == 2) {
#pragma unroll
            for (int gi = 0; gi < 4; ++gi) {
                bf16x8 h = *(const bf16x8*)(vembB + hoff[gi] + kk);
                bf16x8 t = *(const bf16x8*)(vembB + toff[gi] + kk);
                bf16x8 p;
#pragma unroll
                for (int j = 0; j < 8; ++j) p[j] = f2bf(bf2f(h[j]) * bf2f(t[j]));
                *(bf16x8*)&Abuf[bf][wv * 32 + gi * 8 + rr][sl * 8] = p;
            }
        } else {                              // dis + pad (k0 = 2304 or 2368)
            int kb = k0 - 2304;
#pragma unroll
            for (int gi = 0; gi < 4; ++gi) {
                int g   = m0 + wv * 32 + gi * 8 + rr;
                int rdh = dht[g], rdt = dth[g];
                bf16x8 p;
#pragma unroll
                for (int j = 0; j < 8; ++j) {
                    int kkj = kb + gsw * 8 + j;
                    float v = 0.f;
                    if      (kkj < 20) v = dis[rdh * DIS_ + kkj];
                    else if (kkj < 40) v = dis[rdt * DIS_ + (kkj - 20)];
                    p[j] = f2bf(v);
                }
                *(bf16x8*)&Abuf[bf][wv * 32 + gi * 8 + rr][sl * 8] = p;
            }
        }
        // B: lane-linear contiguous 1 KB per dma16 (retiled W1Tile),
        // inst p covers elems [p*512,(p+1)*512) of the 8 KB iter-tile.
        const ushort_t* bbase = W1Tile + ((size_t)it_g * 6 + nt) * 4096;
#pragma unroll
        for (int q = 0; q < 2; ++q) {
            int p = wv * 2 + q;
            dma16(bbase + (size_t)p * 512 + lane * 8, &Bbuf[bf][p][0][0]);
        }
    };

    // fragment addressing (32x32x16: A[m=lane&31][k=(lane>>5)*8+j])
    int half = lane >> 5;
    int lrow = lane & 31;
    int wm   = (wv & 1) * 64;
    int wn   = (wv >> 1) * 32;

    f32x16 acc[2];
#pragma unroll
    for (int i = 0; i < 2; ++i)
#pragma unroll
        for (int r = 0; r < 16; ++r) acc[i][r] = 0.f;

    stage(0, ksl);
    for (int it = 0; it < 19; ++it) {
        int bf = it & 1;
        __syncthreads();                      // drains prev DMA + frag reads
        if (it + 1 < 19) stage(bf ^ 1, 2 * (it + 1) + ksl);
#pragma unroll
        for (int s = 0; s < 4; ++s) {
            int kg   = s * 2 + half;
            int slot = ((kg + lrow) & 7) * 8;  // swizzled slot for this row set
            bf16x8 a0 = *(bf16x8*)&Abuf[bf][wm + lrow][slot];
            bf16x8 a1 = *(bf16x8*)&Abuf[bf][wm + 32 + lrow][slot];
            bf16x8 b0 = *(bf16x8*)&Bbuf[bf][kg][wn + lrow][0];
            acc[0] = __builtin_amdgcn_mfma_f32_32x32x16_bf16(a0, b0, acc[0], 0, 0, 0);
            acc[1] = __builtin_amdgcn_mfma_f32_32x32x16_bf16(a1, b0, acc[1], 0, 0, 0);
        }
    }

    // epilogue: plain bf16 stores to this slice's partial buffer
    // C/D 32x32 layout: col=lane&31, row=(reg&3)+8*(reg>>2)+4*(lane>>5)
    ushort_t* outp = hiddenS + (size_t)ksl * SLICE_;
    int col = n0 + wn + lrow;
#pragma unroll
    for (int fm = 0; fm < 2; ++fm) {
#pragma unroll
        for (int r = 0; r < 16; ++r) {
            int row = m0 + wm + fm * 32 + (r & 3) + 8 * (r >> 2) + 4 * half;
            outp[(size_t)row * HID_ + col] = (ushort_t)f2bf(acc[fm][r]);
        }
    }
}

// ---------------------------------------------------------------------------
// Kernel 4: MFMA GEMM2 + bias; A = relu(slice0+slice1) fused in staging.
// ---------------------------------------------------------------------------
__global__ __launch_bounds__(256) void gemm2_kernel(
    const ushort_t* __restrict__ hiddenS, const ushort_t* __restrict__ W2T,
    const float* __restrict__ b2, float* __restrict__ out)
{
    __shared__ ushort_t As[32][72];
    __shared__ ushort_t Bs[128][72];

    int m0  = blockIdx.x * 32;
    int tid = threadIdx.x;

    int arow = tid >> 3;             // 0..31
    int akk  = (tid & 7) * 8;

    bf16x8 pA; bf16x8 pB[4];
    auto loadAB = [&](int k0) {
        const ushort_t* hp = hiddenS + (size_t)(m0 + arow) * HID_ + k0 + akk;
        bf16x8 x0 = *(const bf16x8*)hp;
        bf16x8 x1 = *(const bf16x8*)(hp + SLICE_);
#pragma unroll
        for (int j = 0; j < 8; ++j)
            pA[j] = f2bf(fmaxf(bf2f(x0[j]) + bf2f(x1[j]), 0.f));
#pragma unroll
        for (int e = 0; e < 4; ++e)
            pB[e] = *(const bf16x8*)(W2T + (size_t)(arow + e * 32) * HID_ + k0 + akk);
    };

    int w    = tid >> 6;
    int lane = tid & 63;
    int wm = (w & 1) * 16;
    int wn = (w >> 1) * 64;
    int lr = lane & 15, lq = lane >> 4;

    f32x4 acc[4];
#pragma unroll
    for (int e = 0; e < 4; ++e) acc[e] = (f32x4){0.f, 0.f, 0.f, 0.f};

    loadAB(0);
    for (int k0 = 0; k0 < HID_; k0 += 64) {
        __syncthreads();
        *(bf16x8*)&As[arow][akk] = pA;
#pragma unroll
        for (int e = 0; e < 4; ++e)
            *(bf16x8*)&Bs[arow + e * 32][akk] = pB[e];
        __syncthreads();
        if (k0 + 64 < HID_) loadAB(k0 + 64);
#pragma unroll
        for (int ks = 0; ks < 2; ++ks) {
            int kb = ks * 32 + lq * 8;
            bf16x8 a = *(bf16x8*)&As[wm + lr][kb];
#pragma unroll
            for (int nf = 0; nf < 4; ++nf) {
                bf16x8 bb = *(bf16x8*)&Bs[wn + nf * 16 + lr][kb];
                acc[nf] = __builtin_amdgcn_mfma_f32_16x16x32_bf16(a, bb, acc[nf], 0, 0, 0);
            }
        }
    }

    int grow = m0 + wm + lq * 4;
#pragma unroll
    for (int nf = 0; nf < 4; ++nf) {
        int col = wn + nf * 16 + lr;
        if (col < REL_) {
            float bias = b2[col];
#pragma unroll
            for (int r = 0; r < 4; ++r)
                out[(size_t)(grow + r) * REL_ + col] = acc[nf][r] + bias;
        }
    }
}

// ---------------------------------------------------------------------------
extern "C" void kernel_launch(void* const* d_in, const int* in_sizes, int n_in,
                              void* d_out, int out_size, void* d_ws, size_t ws_size,
                              hipStream_t stream)
{
    const float* sr    = (const float*)d_in[0];
    const int*   spans = (const int*)  d_in[1];
    const int*   vidx  = (const int*)  d_in[3];
    const int*   vmask = (const int*)  d_in[4];
    const int*   ht    = (const int*)  d_in[5];
    const int*   dht   = (const int*)  d_in[7];
    const int*   dth   = (const int*)  d_in[8];
    const float* dis   = (const float*)d_in[9];
    const float* W1    = (const float*)d_in[10];
    const float* W2    = (const float*)d_in[11];
    const float* b2    = (const float*)d_in[12];
    float* out = (float*)d_out;

    // ws (all bf16): span | vemb | W1Tile | W2T | hiddenS[2]  ~24 MB
    ushort_t* span_emb = (ushort_t*)d_ws;                     // 4096*768
    ushort_t* vembB    = span_emb + (size_t)B_ * NS_ * D_;    // 2048*768
    ushort_t* W1Tile   = vembB + (size_t)B_ * V_ * D_;        // 38*6*4096
    ushort_t* W2T      = W1Tile + (size_t)NIT_ * 6 * 4096;    // 128*384
    ushort_t* hiddenS  = W2T + (size_t)N2P_ * HID_;           // 2 x 8192*384

    prep_kernel<<<4096 + 608 + 32, 192, 0, stream>>>(
        sr, spans, W1, W2, span_emb, W1Tile, W2T);
    vertex_kernel<<<B_ * V_, 192, 0, stream>>>(span_emb, vidx, vmask, vembB);

    dim3 g1((B_ * R_) / BM1, HID_ / BN1, 2);   // 64 x 6 x 2 = 768 blocks
    gemm1_kernel<<<g1, 256, 0, stream>>>(vembB, ht, dht, dth, dis, W1Tile, hiddenS);

    gemm2_kernel<<<(B_ * R_) / 32, 256, 0, stream>>>(hiddenS, W2T, b2, out);
}

// Round 10
// 151.773 us; speedup vs baseline: 1.0187x; 1.0187x over previous
//
#include <hip/hip_runtime.h>
#include <cstdint>
#include <cstddef>

// Problem constants
#define B_    16
#define S_    1024
#define D_    768
#define NS_   256
#define V_    128
#define C_    6
#define R_    512
#define REL_  97
#define HID_  384
#define DIS_  20
#define K1_   2344   // true feat width
#define KP_   2432   // permuted+padded K (38*64) -> 19 iters per split-K slice
#define NIT_  38
#define N2P_  128    // gemm2 padded N

#define BM1   128
#define BN1   64
#define SLICE_ ((size_t)8192 * HID_)   // one split-K partial (bf16 elems)

typedef unsigned short ushort_t;
typedef unsigned int   u32;
typedef short bf16x4 __attribute__((ext_vector_type(4)));
typedef short bf16x8 __attribute__((ext_vector_type(8)));
typedef float f32x4  __attribute__((ext_vector_type(4)));
typedef float f32x16 __attribute__((ext_vector_type(16)));

__device__ __forceinline__ float bf2f(short s) {
    return __uint_as_float(((unsigned int)(unsigned short)s) << 16);
}
__device__ __forceinline__ short f2bf(float x) {   // RNE
    union { float f; unsigned int u; } c; c.f = x;
    unsigned int r = (c.u + 0x7fffu + ((c.u >> 16) & 1u)) >> 16;
    return (short)(unsigned short)r;
}

// async global->LDS, 16 B per lane; LDS dest = wave-uniform base + lane*16
typedef const __attribute__((address_space(1))) u32* gas_t;
typedef __attribute__((address_space(3))) u32*       las_t;
__device__ __forceinline__ void dma16(const void* g, void* l) {
    __builtin_amdgcn_global_load_lds((gas_t)g, (las_t)l, 16, 0, 0);
}

__device__ __forceinline__ int w1_orig(int k) {
    if      (k < 768)  return k;
    else if (k < 1536) return k + 20;
    else if (k < 2304) return k + 40;
    else if (k < 2324) return 768 + (k - 2304);
    else if (k < K1_)  return 1556 + (k - 2324);
    return -1;
}

// ---------------------------------------------------------------------------
// Kernel A (prep), 192 threads, ILP-structured (all loads independent):
//  blocks [0,4096): span max-pool — rows 1..w loaded via block-uniform
//    switch-FALLTHROUGH (loads issue back-to-back, one waitcnt round; rows
//    beyond w never issue -> ~44% less read traffic than unconditional-8).
//  blocks [4096,4704): W1 -> W1Tile [it][nt(6)][kg][nn(64)][8], one bf16x8
//    granule per thread (8 coalesced loads + one 16 B store).
//  blocks [4704,4736): W2 (384x97) -> W2T (128x384, n-padded), one granule
//    per thread.
// ---------------------------------------------------------------------------
__global__ __launch_bounds__(192) void prep_kernel(
    const float* __restrict__ sr, const int* __restrict__ spans,
    const float* __restrict__ W1, const float* __restrict__ W2,
    ushort_t* __restrict__ span_emb, ushort_t* __restrict__ W1Tile,
    ushort_t* __restrict__ W2T)
{
    int blk = blockIdx.x;
    int tid = threadIdx.x;
    if (blk < 4096) {
        int bn    = blk;
        int b     = bn >> 8;                 // NS = 256
        int start = spans[2 * bn];
        int end   = spans[2 * bn + 1];
        int w     = end - start;             // 0..7, block-uniform
        const float* base = sr + ((size_t)b * S_ + start) * D_ + tid * 4;
        f32x4 x[8];
        x[0] = *(const f32x4*)base;
        // block-uniform fallthrough: loads for rows 1..w issue consecutively
        switch (w) {
        case 7: x[7] = *(const f32x4*)(base + 7 * D_); [[fallthrough]];
        case 6: x[6] = *(const f32x4*)(base + 6 * D_); [[fallthrough]];
        case 5: x[5] = *(const f32x4*)(base + 5 * D_); [[fallthrough]];
        case 4: x[4] = *(const f32x4*)(base + 4 * D_); [[fallthrough]];
        case 3: x[3] = *(const f32x4*)(base + 3 * D_); [[fallthrough]];
        case 2: x[2] = *(const f32x4*)(base + 2 * D_); [[fallthrough]];
        case 1: x[1] = *(const f32x4*)(base + 1 * D_); break;
        default: break;
        }
        f32x4 m = x[0];
#pragma unroll
        for (int j = 1; j < 8; ++j)
            if (j <= w) {                    // block-uniform predication
#pragma unroll
                for (int c = 0; c < 4; ++c) m[c] = fmaxf(m[c], x[j][c]);
            }
        bf16x4 o;
#pragma unroll
        for (int c = 0; c < 4; ++c) o[c] = f2bf(m[c]);
        *(bf16x4*)(span_emb + (size_t)bn * D_ + tid * 4) = o;
    } else if (blk < 4096 + 608) {
        int flat = (blk - 4096) * 192 + tid; // 0..116735 = 38*6*8*64
        int nn   = flat & 63;
        int kg   = (flat >> 6) & 7;
        int itnt = flat >> 9;                // it*6 + nt, 0..227
        int it   = itnt / 6;
        bf16x8 p;
#pragma unroll
        for (int j = 0; j < 8; ++j) {
            int k = it * 64 + kg * 8 + j;
            int orig = w1_orig(k);
            int n    = (itnt - it * 6) * 64 + nn;
            float v = (orig >= 0) ? W1[(size_t)orig * HID_ + n] : 0.f;
            p[j] = f2bf(v);
        }
        *(bf16x8*)(W1Tile + ((size_t)itnt * 8 + kg) * 512 + nn * 8) = p;
    } else {
        int g  = (blk - 4704) * 192 + tid;   // 0..6143 = 128*384/8
        int n  = g / 48;                     // 0..127
        int k0 = (g - n * 48) * 8;
        bf16x8 p;
#pragma unroll
        for (int j = 0; j < 8; ++j) {
            float v = (n < REL_) ? W2[(size_t)(k0 + j) * REL_ + n] : 0.f;
            p[j] = f2bf(v);
        }
        *(bf16x8*)(W2T + (size_t)n * HID_ + k0) = p;
    }
}

// ---------------------------------------------------------------------------
// Kernel 2: vertex mean (bf16 in/out, f32 accumulate, bf16x4 vectorized).
// ---------------------------------------------------------------------------
__global__ __launch_bounds__(192) void vertex_kernel(
    const ushort_t* __restrict__ span_emb, const int* __restrict__ vidx,
    const int* __restrict__ vmask, ushort_t* __restrict__ vembB)
{
    int bv = blockIdx.x;
    int b  = bv >> 7;                // V = 128
    const int* vi = vidx  + bv * C_;
    const int* vm = vmask + bv * C_;
    int   idxs[C_];
    float ms[C_];
    float cnt = 0.f;
#pragma unroll
    for (int c = 0; c < C_; ++c) {
        idxs[c] = vi[c];
        ms[c]   = (float)vm[c];
        cnt    += ms[c];
    }
    float inv = 1.f / fmaxf(cnt, 1.f);
    int col = threadIdx.x * 4;
    float s[4] = {0.f, 0.f, 0.f, 0.f};
#pragma unroll
    for (int c = 0; c < C_; ++c) {
        if (ms[c] != 0.f) {          // block-uniform branch
            bf16x4 x = *(const bf16x4*)(span_emb +
                        ((size_t)(b * NS_ + idxs[c])) * D_ + col);
#pragma unroll
            for (int q = 0; q < 4; ++q) s[q] += bf2f(x[q]);
        }
    }
    bf16x4 o;
#pragma unroll
    for (int q = 0; q < 4; ++q) o[q] = f2bf(s[q] * inv);
    *(bf16x4*)(vembB + (size_t)bv * D_ + col) = o;
}

// ---------------------------------------------------------------------------
// Kernel 3: fused-gather MFMA GEMM1, split-K=2 (parity-interleaved iters),
// bf16 partials, plain stores.
// Block 128m x 64n; 4 waves (2x2) each 64m x 32n via 2x1 of 32x32x16 MFMA.
// Grid 64 x 6 x 2 = 768 blocks; LDS 48 KB -> exactly 3 blocks/CU, no tail.
// A LDS: swizzled row-major Abuf[row][64], granule g of row r at slot (g+r)&7:
//   DMA lane-linear (8 rows x 8 slots per inst, adjacent lanes cover one
//   row's contiguous 128 B); fragment ds_read_b128 conflict-free via rotation.
// B LDS: granule-plane Bbuf[kg][64][8] (DMA 1 KB contiguous per inst from
//   retiled W1Tile).
// Double-buffered, one barrier/iter, DMA issued post-barrier.
// ---------------------------------------------------------------------------
__global__ __launch_bounds__(256, 3) void gemm1_kernel(
    const ushort_t* __restrict__ vembB, const int* __restrict__ ht,
    const int* __restrict__ dht, const int* __restrict__ dth,
    const float* __restrict__ dis, const ushort_t* __restrict__ W1Tile,
    ushort_t* __restrict__ hiddenS)
{
    __shared__ ushort_t Abuf[2][BM1][64];       // 32 KB (swizzled slots)
    __shared__ ushort_t Bbuf[2][8][BN1][8];     // 16 KB

    int tid  = threadIdx.x;
    int wv   = tid >> 6;
    int lane = tid & 63;
    int m0   = blockIdx.x * BM1;
    int n0   = blockIdx.y * BN1;
    int nt   = blockIdx.y;
    int ksl  = blockIdx.z;                    // 0/1: parity of iters

    int rr  = lane >> 3;                      // row-in-group 0..7
    int sl  = lane & 7;                       // LDS slot 0..7
    int gsw = (sl - rr) & 7;                  // granule this lane fetches

    // per-lane row offsets for its 4 staging rows (element offsets in vembB)
    int hoff[4], toff[4];
#pragma unroll
    for (int gi = 0; gi < 4; ++gi) {
        int row = wv * 32 + gi * 8 + rr;
        int g   = m0 + row;
        int b   = g >> 9;                     // R = 512
        hoff[gi] = (b * V_ + ht[2 * g])     * D_;
        toff[gi] = (b * V_ + ht[2 * g + 1]) * D_;
    }

    auto stage = [&](int bf, int it_g) {
        int k0   = it_g * 64;
        int r    = k0 / 768;                  // block-uniform region id
        int koff = k0 - r * 768;
        int kk   = koff + gsw * 8;            // lane's element offset in region
        if (r == 0) {
#pragma unroll
            for (int gi = 0; gi < 4; ++gi)
                dma16(vembB + hoff[gi] + kk, &Abuf[bf][wv * 32 + gi * 8][0]);
        } else if (r == 1) {
#pragma unroll
            for (int gi = 0; gi < 4; ++gi)
                dma16(vembB + toff[gi] + kk, &Abuf[bf][wv * 32 + gi * 8][0]);
        } else if (r == 2) {
#pragma unroll
            for (int gi = 0; gi < 4; ++gi) {
                bf16x8 h = *(const bf16x8*)(vembB + hoff[gi] + kk);
                bf16x8 t = *(const bf16x8*)(vembB + toff[gi] + kk);
                bf16x8 p;
#pragma unroll
                for (int j = 0; j < 8; ++j) p[j] = f2bf(bf2f(h[j]) * bf2f(t[j]));
                *(bf16x8*)&Abuf[bf][wv * 32 + gi * 8 + rr][sl * 8] = p;
            }
        } else {                              // dis + pad (k0 = 2304 or 2368)
            int kb = k0 - 2304;
#pragma unroll
            for (int gi = 0; gi < 4; ++gi) {
                int g   = m0 + wv * 32 + gi * 8 + rr;
                int rdh = dht[g], rdt = dth[g];
                bf16x8 p;
#pragma unroll
                for (int j = 0; j < 8; ++j) {
                    int kkj = kb + gsw * 8 + j;
                    float v = 0.f;
                    if      (kkj < 20) v = dis[rdh * DIS_ + kkj];
                    else if (kkj < 40) v = dis[rdt * DIS_ + (kkj - 20)];
                    p[j] = f2bf(v);
                }
                *(bf16x8*)&Abuf[bf][wv * 32 + gi * 8 + rr][sl * 8] = p;
            }
        }
        // B: lane-linear contiguous 1 KB per dma16 (retiled W1Tile),
        // inst p covers elems [p*512,(p+1)*512) of the 8 KB iter-tile.
        const ushort_t* bbase = W1Tile + ((size_t)it_g * 6 + nt) * 4096;
#pragma unroll
        for (int q = 0; q < 2; ++q) {
            int p = wv * 2 + q;
            dma16(bbase + (size_t)p * 512 + lane * 8, &Bbuf[bf][p][0][0]);
        }
    };

    // fragment addressing (32x32x16: A[m=lane&31][k=(lane>>5)*8+j])
    int half = lane >> 5;
    int lrow = lane & 31;
    int wm   = (wv & 1) * 64;
    int wn   = (wv >> 1) * 32;

    f32x16 acc[2];
#pragma unroll
    for (int i = 0; i < 2; ++i)
#pragma unroll
        for (int r = 0; r < 16; ++r) acc[i][r] = 0.f;

    stage(0, ksl);
    for (int it = 0; it < 19; ++it) {
        int bf = it & 1;
        __syncthreads();                      // drains prev DMA + frag reads
        if (it + 1 < 19) stage(bf ^ 1, 2 * (it + 1) + ksl);
#pragma unroll
        for (int s = 0; s < 4; ++s) {
            int kg   = s * 2 + half;
            int slot = ((kg + lrow) & 7) * 8;  // swizzled slot for this row set
            bf16x8 a0 = *(bf16x8*)&Abuf[bf][wm + lrow][slot];
            bf16x8 a1 = *(bf16x8*)&Abuf[bf][wm + 32 + lrow][slot];
            bf16x8 b0 = *(bf16x8*)&Bbuf[bf][kg][wn + lrow][0];
            acc[0] = __builtin_amdgcn_mfma_f32_32x32x16_bf16(a0, b0, acc[0], 0, 0, 0);
            acc[1] = __builtin_amdgcn_mfma_f32_32x32x16_bf16(a1, b0, acc[1], 0, 0, 0);
        }
    }

    // epilogue: plain bf16 stores to this slice's partial buffer
    // C/D 32x32 layout: col=lane&31, row=(reg&3)+8*(reg>>2)+4*(lane>>5)
    ushort_t* outp = hiddenS + (size_t)ksl * SLICE_;
    int col = n0 + wn + lrow;
#pragma unroll
    for (int fm = 0; fm < 2; ++fm) {
#pragma unroll
        for (int r = 0; r < 16; ++r) {
            int row = m0 + wm + fm * 32 + (r & 3) + 8 * (r >> 2) + 4 * half;
            outp[(size_t)row * HID_ + col] = (ushort_t)f2bf(acc[fm][r]);
        }
    }
}

// ---------------------------------------------------------------------------
// Kernel 4: MFMA GEMM2 + bias; A = relu(slice0+slice1) fused in staging.
// ---------------------------------------------------------------------------
__global__ __launch_bounds__(256) void gemm2_kernel(
    const ushort_t* __restrict__ hiddenS, const ushort_t* __restrict__ W2T,
    const float* __restrict__ b2, float* __restrict__ out)
{
    __shared__ ushort_t As[32][72];
    __shared__ ushort_t Bs[128][72];

    int m0  = blockIdx.x * 32;
    int tid = threadIdx.x;

    int arow = tid >> 3;             // 0..31
    int akk  = (tid & 7) * 8;

    bf16x8 pA; bf16x8 pB[4];
    auto loadAB = [&](int k0) {
        const ushort_t* hp = hiddenS + (size_t)(m0 + arow) * HID_ + k0 + akk;
        bf16x8 x0 = *(const bf16x8*)hp;
        bf16x8 x1 = *(const bf16x8*)(hp + SLICE_);
#pragma unroll
        for (int j = 0; j < 8; ++j)
            pA[j] = f2bf(fmaxf(bf2f(x0[j]) + bf2f(x1[j]), 0.f));
#pragma unroll
        for (int e = 0; e < 4; ++e)
            pB[e] = *(const bf16x8*)(W2T + (size_t)(arow + e * 32) * HID_ + k0 + akk);
    };

    int w    = tid >> 6;
    int lane = tid & 63;
    int wm = (w & 1) * 16;
    int wn = (w >> 1) * 64;
    int lr = lane & 15, lq = lane >> 4;

    f32x4 acc[4];
#pragma unroll
    for (int e = 0; e < 4; ++e) acc[e] = (f32x4){0.f, 0.f, 0.f, 0.f};

    loadAB(0);
    for (int k0 = 0; k0 < HID_; k0 += 64) {
        __syncthreads();
        *(bf16x8*)&As[arow][akk] = pA;
#pragma unroll
        for (int e = 0; e < 4; ++e)
            *(bf16x8*)&Bs[arow + e * 32][akk] = pB[e];
        __syncthreads();
        if (k0 + 64 < HID_) loadAB(k0 + 64);
#pragma unroll
        for (int ks = 0; ks < 2; ++ks) {
            int kb = ks * 32 + lq * 8;
            bf16x8 a = *(bf16x8*)&As[wm + lr][kb];
#pragma unroll
            for (int nf = 0; nf < 4; ++nf) {
                bf16x8 bb = *(bf16x8*)&Bs[wn + nf * 16 + lr][kb];
                acc[nf] = __builtin_amdgcn_mfma_f32_16x16x32_bf16(a, bb, acc[nf], 0, 0, 0);
            }
        }
    }

    int grow = m0 + wm + lq * 4;
#pragma unroll
    for (int nf = 0; nf < 4; ++nf) {
        int col = wn + nf * 16 + lr;
        if (col < REL_) {
            float bias = b2[col];
#pragma unroll
            for (int r = 0; r < 4; ++r)
                out[(size_t)(grow + r) * REL_ + col] = acc[nf][r] + bias;
        }
    }
}

// ---------------------------------------------------------------------------
extern "C" void kernel_launch(void* const* d_in, const int* in_sizes, int n_in,
                              void* d_out, int out_size, void* d_ws, size_t ws_size,
                              hipStream_t stream)
{
    const float* sr    = (const float*)d_in[0];
    const int*   spans = (const int*)  d_in[1];
    const int*   vidx  = (const int*)  d_in[3];
    const int*   vmask = (const int*)  d_in[4];
    const int*   ht    = (const int*)  d_in[5];
    const int*   dht   = (const int*)  d_in[7];
    const int*   dth   = (const int*)  d_in[8];
    const float* dis   = (const float*)d_in[9];
    const float* W1    = (const float*)d_in[10];
    const float* W2    = (const float*)d_in[11];
    const float* b2    = (const float*)d_in[12];
    float* out = (float*)d_out;

    // ws (all bf16): span | vemb | W1Tile | W2T | hiddenS[2]  ~24 MB
    ushort_t* span_emb = (ushort_t*)d_ws;                     // 4096*768
    ushort_t* vembB    = span_emb + (size_t)B_ * NS_ * D_;    // 2048*768
    ushort_t* W1Tile   = vembB + (size_t)B_ * V_ * D_;        // 38*6*4096
    ushort_t* W2T      = W1Tile + (size_t)NIT_ * 6 * 4096;    // 128*384
    ushort_t* hiddenS  = W2T + (size_t)N2P_ * HID_;           // 2 x 8192*384

    prep_kernel<<<4096 + 608 + 32, 192, 0, stream>>>(
        sr, spans, W1, W2, span_emb, W1Tile, W2T);
    vertex_kernel<<<B_ * V_, 192, 0, stream>>>(span_emb, vidx, vmask, vembB);

    dim3 g1((B_ * R_) / BM1, HID_ / BN1, 2);   // 64 x 6 x 2 = 768 blocks
    gemm1_kernel<<<g1, 256, 0, stream>>>(vembB, ht, dht, dth, dis, W1Tile, hiddenS);

    gemm2_kernel<<<(B_ * R_) / 32, 256, 0, stream>>>(hiddenS, W2T, b2, out);
}